// Round 2
// baseline (1443.318 us; speedup 1.0000x reference)
//
#include <hip/hip_runtime.h>
#include <cmath>

#define NN 100000
#define NE 1600000
#define HD 128

// ---------------- GEMM: out[n][128] = A[n][K] @ W[K][128], K <= 144 ----------
__global__ __launch_bounds__(256) void gemm_kernel(
    const float* __restrict__ A, const float* __restrict__ W,
    float* __restrict__ out, int n, int K) {
  __shared__ float Wl[144 * 128];   // 73.7 KB, zero-padded rows K..143
  __shared__ float At[16][68];      // transposed A tile, padded stride
  int t = threadIdx.x;
  for (int i = t; i < 144 * 128; i += 256) {
    int k = i >> 7;
    Wl[i] = (k < K) ? W[i] : 0.0f;
  }
  int brow = blockIdx.x * 64;
  int cg = t & 15;      // col group: 8 cols
  int rg = t >> 4;      // row group: 4 rows
  int srow = t >> 2;    // staging row 0..63
  int skq = (t & 3) * 4;
  float acc[4][8];
#pragma unroll
  for (int r = 0; r < 4; ++r)
#pragma unroll
    for (int c = 0; c < 8; ++c) acc[r][c] = 0.f;
  int ntiles = (K + 15) >> 4;
  __syncthreads();
  for (int tb = 0; tb < ntiles; ++tb) {
    int kbase = tb << 4;
    int gr = brow + srow;
#pragma unroll
    for (int i = 0; i < 4; ++i) {
      int k = kbase + skq + i;
      float v = 0.f;
      if (gr < n && k < K) v = A[(size_t)gr * K + k];
      At[skq + i][srow] = v;
    }
    __syncthreads();
#pragma unroll
    for (int kk = 0; kk < 16; ++kk) {
      float4 a = *(const float4*)&At[kk][rg * 4];
      const float* wr = &Wl[(kbase + kk) * 128 + cg * 8];
      float4 w0 = *(const float4*)wr;
      float4 w1 = *(const float4*)(wr + 4);
      float av[4] = {a.x, a.y, a.z, a.w};
      float wv[8] = {w0.x, w0.y, w0.z, w0.w, w1.x, w1.y, w1.z, w1.w};
#pragma unroll
      for (int r = 0; r < 4; ++r)
#pragma unroll
        for (int c = 0; c < 8; ++c) acc[r][c] += av[r] * wv[c];
    }
    __syncthreads();
  }
#pragma unroll
  for (int r = 0; r < 4; ++r) {
    int grow = brow + rg * 4 + r;
    if (grow < n) {
      float4 o0 = make_float4(acc[r][0], acc[r][1], acc[r][2], acc[r][3]);
      float4 o1 = make_float4(acc[r][4], acc[r][5], acc[r][6], acc[r][7]);
      float* op = out + (size_t)grow * HD + cg * 8;
      *(float4*)op = o0;
      *(float4*)(op + 4) = o1;
    }
  }
}

// ---------------- degree count (int atomics) ----------------
__global__ void cnt_kernel(const int* __restrict__ ei, int* __restrict__ cnt, int e) {
  int i = blockIdx.x * blockDim.x + threadIdx.x;
  if (i < e) atomicAdd(&cnt[ei[(size_t)e + i]], 1);
}

__global__ void dinv_kernel(const int* __restrict__ cnt, float* __restrict__ dinv, int n) {
  int i = blockIdx.x * blockDim.x + threadIdx.x;
  if (i < n) dinv[i] = 1.0f / sqrtf((float)cnt[i] + 1.0f);
}

// ---------------- exclusive scan (3 kernels, 1024 elems/block) ----------------
__global__ __launch_bounds__(256) void scan1(const int* __restrict__ cnt, int* __restrict__ excl,
                                             int* __restrict__ partials, int n) {
  __shared__ int sd[256];
  int t = threadIdx.x;
  int base = blockIdx.x * 1024 + t * 4;
  int v[4]; int s = 0;
#pragma unroll
  for (int i = 0; i < 4; ++i) { int idx = base + i; v[i] = (idx < n) ? cnt[idx] : 0; s += v[i]; }
  sd[t] = s;
  __syncthreads();
  for (int off = 1; off < 256; off <<= 1) {
    int x = (t >= off) ? sd[t - off] : 0;
    __syncthreads();
    if (t >= off) sd[t] += x;
    __syncthreads();
  }
  if (t == 255) partials[blockIdx.x] = sd[255];
  int run = sd[t] - s;
#pragma unroll
  for (int i = 0; i < 4; ++i) { int idx = base + i; if (idx < n) excl[idx] = run; run += v[i]; }
}

__global__ __launch_bounds__(256) void scan2(int* __restrict__ partials, int np) {
  __shared__ int sd[256];
  int t = threadIdx.x;
  int v = (t < np) ? partials[t] : 0;
  sd[t] = v;
  __syncthreads();
  for (int off = 1; off < 256; off <<= 1) {
    int x = (t >= off) ? sd[t - off] : 0;
    __syncthreads();
    if (t >= off) sd[t] += x;
    __syncthreads();
  }
  if (t < np) partials[t] = sd[t] - v;
}

__global__ void scan3(int* __restrict__ rowptr, const int* __restrict__ partials, int n, int etot) {
  int i = blockIdx.x * blockDim.x + threadIdx.x;
  if (i < n) rowptr[i] += partials[i >> 10];
  if (i == 0) rowptr[n] = etot;
}

// ---------------- CSR fill ----------------
__global__ void fill_kernel(const int* __restrict__ ei, const float* __restrict__ dinv,
                            const int* __restrict__ rowptr, int* __restrict__ cursor,
                            int* __restrict__ esrc, float* __restrict__ ecoef, int e) {
  int i = blockIdx.x * blockDim.x + threadIdx.x;
  if (i >= e) return;
  int s = ei[i];
  int d = ei[(size_t)e + i];
  int p = atomicAdd(&cursor[d], 1);
  int idx = rowptr[d] + p;
  esrc[idx] = s;
  ecoef[idx] = dinv[s] * dinv[d];
}

// ---------------- aggregation: one wave per dst node ----------------
__global__ __launch_bounds__(256) void agg_kernel(
    const float* __restrict__ h, const float* __restrict__ dinv,
    const int* __restrict__ rowptr, const int* __restrict__ esrc,
    const float* __restrict__ ecoef, const float* __restrict__ bias,
    float* __restrict__ out, int n) {
  int wid = (int)((blockIdx.x * (size_t)blockDim.x + threadIdx.x) >> 6);
  int lane = threadIdx.x & 63;
  if (wid >= n) return;
  float di = dinv[wid];
  float2 hs = *(const float2*)(h + (size_t)wid * HD + lane * 2);
  float2 acc;
  acc.x = hs.x * di * di;
  acc.y = hs.y * di * di;
  int beg = rowptr[wid], end = rowptr[wid + 1];
  for (int j = beg; j < end; ++j) {
    int s = esrc[j];
    float c = ecoef[j];
    float2 v = *(const float2*)(h + (size_t)s * HD + lane * 2);
    acc.x += v.x * c;
    acc.y += v.y * c;
  }
  float2 b = *(const float2*)(bias + lane * 2);
  float2 o;
  o.x = tanhf(acc.x + b.x);
  o.y = tanhf(acc.y + b.y);
  *(float2*)(out + (size_t)wid * HD + lane * 2) = o;
}

extern "C" void kernel_launch(void* const* d_in, const int* in_sizes, int n_in,
                              void* d_out, int out_size, void* d_ws, size_t ws_size,
                              hipStream_t stream) {
  const float* x = (const float*)d_in[0];
  const int* ei = (const int*)d_in[1];   // harness delivers integer inputs as int32
  const float* W0 = (const float*)d_in[2];
  const float* b0 = (const float*)d_in[3];
  const float* W1 = (const float*)d_in[4];
  const float* b1 = (const float*)d_in[5];
  const float* W2 = (const float*)d_in[6];
  const float* b2 = (const float*)d_in[7];
  const float* W3 = (const float*)d_in[8];
  const float* b3 = (const float*)d_in[9];
  float* out = (float*)d_out;

  char* ws = (char*)d_ws;
  size_t off = 0;
  auto alloc = [&](size_t bytes) -> void* {
    void* p = ws + off;
    off += (bytes + 255) & ~(size_t)255;
    return p;
  };
  int*   cnt      = (int*)alloc((size_t)NN * 4);
  int*   cursor   = (int*)alloc((size_t)NN * 4);
  int*   rowptr   = (int*)alloc((size_t)(NN + 1) * 4);
  int*   partials = (int*)alloc(256 * 4);
  float* dinv     = (float*)alloc((size_t)NN * 4);
  int*   esrc     = (int*)alloc((size_t)NE * 4);
  float* ecoef    = (float*)alloc((size_t)NE * 4);
  float* hbuf     = (float*)alloc((size_t)NN * HD * 4);
  // total ws: ~66 MB. d_out doubles as the activation ping-pong buffer.

  hipMemsetAsync(cnt, 0, (size_t)NN * 4, stream);
  hipMemsetAsync(cursor, 0, (size_t)NN * 4, stream);

  int eb = (NE + 255) / 256;
  cnt_kernel<<<eb, 256, 0, stream>>>(ei, cnt, NE);
  int nb1 = (NN + 1023) / 1024;
  scan1<<<nb1, 256, 0, stream>>>(cnt, rowptr, partials, NN);
  scan2<<<1, 256, 0, stream>>>(partials, nb1);
  scan3<<<(NN + 255) / 256, 256, 0, stream>>>(rowptr, partials, NN, NE);
  dinv_kernel<<<(NN + 255) / 256, 256, 0, stream>>>(cnt, dinv, NN);
  fill_kernel<<<eb, 256, 0, stream>>>(ei, dinv, rowptr, cursor, esrc, ecoef, NE);

  int gb = (NN + 63) / 64;
  int ab = (NN + 3) / 4;   // 4 waves per 256-thread block, 1 wave per node

  // layer 0: x -> hbuf -> d_out
  gemm_kernel<<<gb, 256, 0, stream>>>(x, W0, hbuf, NN, 133);
  agg_kernel<<<ab, 256, 0, stream>>>(hbuf, dinv, rowptr, esrc, ecoef, b0, out, NN);
  // layer 1: d_out -> hbuf -> d_out
  gemm_kernel<<<gb, 256, 0, stream>>>(out, W1, hbuf, NN, HD);
  agg_kernel<<<ab, 256, 0, stream>>>(hbuf, dinv, rowptr, esrc, ecoef, b1, out, NN);
  // layer 2
  gemm_kernel<<<gb, 256, 0, stream>>>(out, W2, hbuf, NN, HD);
  agg_kernel<<<ab, 256, 0, stream>>>(hbuf, dinv, rowptr, esrc, ecoef, b2, out, NN);
  // layer 3
  gemm_kernel<<<gb, 256, 0, stream>>>(out, W3, hbuf, NN, HD);
  agg_kernel<<<ab, 256, 0, stream>>>(hbuf, dinv, rowptr, esrc, ecoef, b3, out, NN);
}

// Round 3
// 1163.063 us; speedup vs baseline: 1.2410x; 1.2410x over previous
//
#include <hip/hip_runtime.h>
#include <cmath>

#define NN 100000
#define NE 1600000
#define HD 128

typedef __attribute__((ext_vector_type(8))) short bf16x8;
typedef __attribute__((ext_vector_type(4))) float f32x4;

__device__ inline short f2bf(float f) {
  union { float f; unsigned u; } x; x.f = f;
  unsigned r = x.u + 0x7fff + ((x.u >> 16) & 1);
  return (short)(r >> 16);
}
__device__ inline float bf2f(short s) {
  union { float f; unsigned u; } x;
  x.u = ((unsigned)(unsigned short)s) << 16;
  return x.f;
}
__device__ inline void split2(float v, short& hi, short& lo) {
  hi = f2bf(v);
  lo = f2bf(v - bf2f(hi));
}

// ---------------- MFMA GEMM: out[n][128] = A[n][K] @ W[K][128] --------------
// 3-term bf16 split for fp32-level accuracy. W staged once in LDS in fragment
// order (hi+lo); A fragments loaded straight from global (coalesced 16x128B).
// Block: 256 threads = 4 waves; wave owns 64 rows x 128 cols.
template <int KST, bool VEC>
__global__ __launch_bounds__(256, 2) void mfma_gemm(
    const float* __restrict__ A, const float* __restrict__ W,
    float* __restrict__ out, int n, int K) {
  __shared__ short Whi[KST * 8 * 64 * 8];
  __shared__ short Wlo[KST * 8 * 64 * 8];
  int t = threadIdx.x;
  // stage W (f32 -> bf16 hi/lo, fragment order)
  for (int i = t; i < KST * 32 * 128; i += 256) {
    int k = i >> 7, col = i & 127;
    float v = (k < K) ? W[k * 128 + col] : 0.f;
    short hi, lo;
    split2(v, hi, lo);
    int off = (((k >> 5) * 8 + (col >> 4)) * 64 + ((k >> 3) & 3) * 16 + (col & 15)) * 8 + (k & 7);
    Whi[off] = hi;
    Wlo[off] = lo;
  }
  __syncthreads();

  int wave = t >> 6, lane = t & 63;
  int lrow = lane & 15, khalf = lane >> 4;
  int r0 = blockIdx.x * 256 + wave * 64;

  f32x4 acc[4][8];
#pragma unroll
  for (int rf = 0; rf < 4; ++rf)
#pragma unroll
    for (int cf = 0; cf < 8; ++cf) acc[rf][cf] = (f32x4){0.f, 0.f, 0.f, 0.f};

#pragma unroll
  for (int ks = 0; ks < KST; ++ks) {
    bf16x8 ahi[4], alo[4];
#pragma unroll
    for (int rf = 0; rf < 4; ++rf) {
      int row = r0 + rf * 16 + lrow;
      float v[8];
      if (VEC) {
        if (row < n) {
          const float4* p = (const float4*)(A + (size_t)row * K + ks * 32 + khalf * 8);
          float4 a = p[0], b = p[1];
          v[0] = a.x; v[1] = a.y; v[2] = a.z; v[3] = a.w;
          v[4] = b.x; v[5] = b.y; v[6] = b.z; v[7] = b.w;
        } else {
#pragma unroll
          for (int i = 0; i < 8; ++i) v[i] = 0.f;
        }
      } else {
#pragma unroll
        for (int i = 0; i < 8; ++i) {
          int k = ks * 32 + khalf * 8 + i;
          v[i] = (row < n && k < K) ? A[(size_t)row * K + k] : 0.f;
        }
      }
#pragma unroll
      for (int i = 0; i < 8; ++i) {
        short hi, lo;
        split2(v[i], hi, lo);
        ahi[rf][i] = hi;
        alo[rf][i] = lo;
      }
    }
#pragma unroll
    for (int cf = 0; cf < 8; ++cf) {
      int boff = ((ks * 8 + cf) * 64 + lane) * 8;
      bf16x8 bhi = *(bf16x8*)&Whi[boff];
      bf16x8 blo = *(bf16x8*)&Wlo[boff];
#pragma unroll
      for (int rf = 0; rf < 4; ++rf) {
        acc[rf][cf] = __builtin_amdgcn_mfma_f32_16x16x32_bf16(ahi[rf], bhi, acc[rf][cf], 0, 0, 0);
        acc[rf][cf] = __builtin_amdgcn_mfma_f32_16x16x32_bf16(ahi[rf], blo, acc[rf][cf], 0, 0, 0);
        acc[rf][cf] = __builtin_amdgcn_mfma_f32_16x16x32_bf16(alo[rf], bhi, acc[rf][cf], 0, 0, 0);
      }
    }
  }

#pragma unroll
  for (int rf = 0; rf < 4; ++rf)
#pragma unroll
    for (int cf = 0; cf < 8; ++cf) {
      int rowb = r0 + rf * 16 + khalf * 4;
      int col = cf * 16 + lrow;
#pragma unroll
      for (int j = 0; j < 4; ++j) {
        int row = rowb + j;
        if (row < n) out[(size_t)row * 128 + col] = acc[rf][cf][j];
      }
    }
}

// ---------------- degree count (int atomics) ----------------
__global__ void cnt_kernel(const int* __restrict__ ei, int* __restrict__ cnt, int e) {
  int i = blockIdx.x * blockDim.x + threadIdx.x;
  if (i < e) atomicAdd(&cnt[ei[(size_t)e + i]], 1);
}

__global__ void dinv_kernel(const int* __restrict__ cnt, float* __restrict__ dinv, int n) {
  int i = blockIdx.x * blockDim.x + threadIdx.x;
  if (i < n) dinv[i] = 1.0f / sqrtf((float)cnt[i] + 1.0f);
}

// ---------------- exclusive scan (3 kernels, 1024 elems/block) ----------------
__global__ __launch_bounds__(256) void scan1(const int* __restrict__ cnt, int* __restrict__ excl,
                                             int* __restrict__ partials, int n) {
  __shared__ int sd[256];
  int t = threadIdx.x;
  int base = blockIdx.x * 1024 + t * 4;
  int v[4]; int s = 0;
#pragma unroll
  for (int i = 0; i < 4; ++i) { int idx = base + i; v[i] = (idx < n) ? cnt[idx] : 0; s += v[i]; }
  sd[t] = s;
  __syncthreads();
  for (int off = 1; off < 256; off <<= 1) {
    int x = (t >= off) ? sd[t - off] : 0;
    __syncthreads();
    if (t >= off) sd[t] += x;
    __syncthreads();
  }
  if (t == 255) partials[blockIdx.x] = sd[255];
  int run = sd[t] - s;
#pragma unroll
  for (int i = 0; i < 4; ++i) { int idx = base + i; if (idx < n) excl[idx] = run; run += v[i]; }
}

__global__ __launch_bounds__(256) void scan2(int* __restrict__ partials, int np) {
  __shared__ int sd[256];
  int t = threadIdx.x;
  int v = (t < np) ? partials[t] : 0;
  sd[t] = v;
  __syncthreads();
  for (int off = 1; off < 256; off <<= 1) {
    int x = (t >= off) ? sd[t - off] : 0;
    __syncthreads();
    if (t >= off) sd[t] += x;
    __syncthreads();
  }
  if (t < np) partials[t] = sd[t] - v;
}

__global__ void scan3(int* __restrict__ rowptr, const int* __restrict__ partials, int n, int etot) {
  int i = blockIdx.x * blockDim.x + threadIdx.x;
  if (i < n) rowptr[i] += partials[i >> 10];
  if (i == 0) rowptr[n] = etot;
}

// ---------------- CSR fill ----------------
__global__ void fill_kernel(const int* __restrict__ ei, const float* __restrict__ dinv,
                            const int* __restrict__ rowptr, int* __restrict__ cursor,
                            int* __restrict__ esrc, float* __restrict__ ecoef, int e) {
  int i = blockIdx.x * blockDim.x + threadIdx.x;
  if (i >= e) return;
  int s = ei[i];
  int d = ei[(size_t)e + i];
  int p = atomicAdd(&cursor[d], 1);
  int idx = rowptr[d] + p;
  esrc[idx] = s;
  ecoef[idx] = dinv[s] * dinv[d];
}

// ---------------- aggregation: one wave per dst node ----------------
__global__ __launch_bounds__(256) void agg_kernel(
    const float* __restrict__ h, const float* __restrict__ dinv,
    const int* __restrict__ rowptr, const int* __restrict__ esrc,
    const float* __restrict__ ecoef, const float* __restrict__ bias,
    float* __restrict__ out, int n) {
  int wid = (int)((blockIdx.x * (size_t)blockDim.x + threadIdx.x) >> 6);
  int lane = threadIdx.x & 63;
  if (wid >= n) return;
  float di = dinv[wid];
  float2 hs = *(const float2*)(h + (size_t)wid * HD + lane * 2);
  float2 acc;
  acc.x = hs.x * di * di;
  acc.y = hs.y * di * di;
  int beg = rowptr[wid], end = rowptr[wid + 1];
  for (int j = beg; j < end; ++j) {
    int s = esrc[j];
    float c = ecoef[j];
    float2 v = *(const float2*)(h + (size_t)s * HD + lane * 2);
    acc.x += v.x * c;
    acc.y += v.y * c;
  }
  float2 b = *(const float2*)(bias + lane * 2);
  float2 o;
  o.x = tanhf(acc.x + b.x);
  o.y = tanhf(acc.y + b.y);
  *(float2*)(out + (size_t)wid * HD + lane * 2) = o;
}

extern "C" void kernel_launch(void* const* d_in, const int* in_sizes, int n_in,
                              void* d_out, int out_size, void* d_ws, size_t ws_size,
                              hipStream_t stream) {
  const float* x = (const float*)d_in[0];
  const int* ei = (const int*)d_in[1];   // integer inputs arrive as int32
  const float* W0 = (const float*)d_in[2];
  const float* b0 = (const float*)d_in[3];
  const float* W1 = (const float*)d_in[4];
  const float* b1 = (const float*)d_in[5];
  const float* W2 = (const float*)d_in[6];
  const float* b2 = (const float*)d_in[7];
  const float* W3 = (const float*)d_in[8];
  const float* b3 = (const float*)d_in[9];
  float* out = (float*)d_out;

  char* ws = (char*)d_ws;
  size_t off = 0;
  auto alloc = [&](size_t bytes) -> void* {
    void* p = ws + off;
    off += (bytes + 255) & ~(size_t)255;
    return p;
  };
  int*   cnt      = (int*)alloc((size_t)NN * 4);
  int*   cursor   = (int*)alloc((size_t)NN * 4);
  int*   rowptr   = (int*)alloc((size_t)(NN + 1) * 4);
  int*   partials = (int*)alloc(256 * 4);
  float* dinv     = (float*)alloc((size_t)NN * 4);
  int*   esrc     = (int*)alloc((size_t)NE * 4);
  float* ecoef    = (float*)alloc((size_t)NE * 4);
  float* hbuf     = (float*)alloc((size_t)NN * HD * 4);
  // ~66 MB ws. d_out doubles as the activation ping-pong buffer.

  hipMemsetAsync(cnt, 0, (size_t)NN * 4, stream);
  hipMemsetAsync(cursor, 0, (size_t)NN * 4, stream);

  int eb = (NE + 255) / 256;
  cnt_kernel<<<eb, 256, 0, stream>>>(ei, cnt, NE);
  int nb1 = (NN + 1023) / 1024;
  scan1<<<nb1, 256, 0, stream>>>(cnt, rowptr, partials, NN);
  scan2<<<1, 256, 0, stream>>>(partials, nb1);
  scan3<<<(NN + 255) / 256, 256, 0, stream>>>(rowptr, partials, NN, NE);
  dinv_kernel<<<(NN + 255) / 256, 256, 0, stream>>>(cnt, dinv, NN);
  fill_kernel<<<eb, 256, 0, stream>>>(ei, dinv, rowptr, cursor, esrc, ecoef, NE);

  int gb = (NN + 255) / 256;   // 256 rows per block
  int ab = (NN + 3) / 4;       // 1 wave per node

  // layer 0: x -> hbuf -> d_out   (K=133, unaligned rows -> scalar A loads)
  mfma_gemm<5, false><<<gb, 256, 0, stream>>>(x, W0, hbuf, NN, 133);
  agg_kernel<<<ab, 256, 0, stream>>>(hbuf, dinv, rowptr, esrc, ecoef, b0, out, NN);
  // layers 1-3: K=128, vectorized A loads
  mfma_gemm<4, true><<<gb, 256, 0, stream>>>(out, W1, hbuf, NN, HD);
  agg_kernel<<<ab, 256, 0, stream>>>(hbuf, dinv, rowptr, esrc, ecoef, b1, out, NN);
  mfma_gemm<4, true><<<gb, 256, 0, stream>>>(out, W2, hbuf, NN, HD);
  agg_kernel<<<ab, 256, 0, stream>>>(hbuf, dinv, rowptr, esrc, ecoef, b2, out, NN);
  mfma_gemm<4, true><<<gb, 256, 0, stream>>>(out, W3, hbuf, NN, HD);
  agg_kernel<<<ab, 256, 0, stream>>>(hbuf, dinv, rowptr, esrc, ecoef, b3, out, NN);
}

// Round 7
// 947.624 us; speedup vs baseline: 1.5231x; 1.2273x over previous
//
#include <hip/hip_runtime.h>
#include <cmath>

#define NN 100000
#define NE 1600000
#define HD 128

typedef __attribute__((ext_vector_type(8))) short bf16x8;
typedef __attribute__((ext_vector_type(4))) float f32x4;

__device__ inline short f2bf(float f) {
  union { float f; unsigned u; } x; x.f = f;
  unsigned r = x.u + 0x7fff + ((x.u >> 16) & 1);
  return (short)(r >> 16);
}
__device__ inline float bf2f(short s) {
  union { float f; unsigned u; } x;
  x.u = ((unsigned)(unsigned short)s) << 16;
  return x.f;
}
__device__ inline void split2(float v, short& hi, short& lo) {
  hi = f2bf(v);
  lo = f2bf(v - bf2f(hi));
}

// ---------------- MFMA GEMM: out[n][128] = A[n][K] @ W[K][128] --------------
// 3-term bf16 split (hi*hi + hi*lo + lo*hi) for fp32-level accuracy.
// W staged once in LDS in fragment order; A k-slices double-buffered in
// registers (prefetch ks+1 while MFMAing ks). Wave owns 64 rows x 128 cols.
template <int KST, bool VEC>
__global__ __launch_bounds__(256, 2) void mfma_gemm(
    const float* __restrict__ A, const float* __restrict__ W,
    float* __restrict__ out, int n, int K) {
  __shared__ short Whi[KST * 8 * 64 * 8];
  __shared__ short Wlo[KST * 8 * 64 * 8];
  int t = threadIdx.x;
  for (int i = t; i < KST * 32 * 128; i += 256) {
    int k = i >> 7, col = i & 127;
    float v = (k < K) ? W[k * 128 + col] : 0.f;
    short hi, lo;
    split2(v, hi, lo);
    int off = (((k >> 5) * 8 + (col >> 4)) * 64 + ((k >> 3) & 3) * 16 + (col & 15)) * 8 + (k & 7);
    Whi[off] = hi;
    Wlo[off] = lo;
  }
  __syncthreads();

  int wave = t >> 6, lane = t & 63;
  int lrow = lane & 15, khalf = lane >> 4;
  int r0 = blockIdx.x * 256 + wave * 64;

  f32x4 acc[4][8];
#pragma unroll
  for (int rf = 0; rf < 4; ++rf)
#pragma unroll
    for (int cf = 0; cf < 8; ++cf) acc[rf][cf] = (f32x4){0.f, 0.f, 0.f, 0.f};

  float vbuf[2][4][8];

  // A k-slice loader: 8 floats per rf (16 rows x 32 k per fragment)
  auto loadA = [&](int ks, float v[4][8]) {
#pragma unroll
    for (int rf = 0; rf < 4; ++rf) {
      int row = r0 + rf * 16 + lrow;
      if (VEC) {
        if (row < n) {
          const float4* p = (const float4*)(A + (size_t)row * K + ks * 32 + khalf * 8);
          float4 a = p[0], b = p[1];
          v[rf][0] = a.x; v[rf][1] = a.y; v[rf][2] = a.z; v[rf][3] = a.w;
          v[rf][4] = b.x; v[rf][5] = b.y; v[rf][6] = b.z; v[rf][7] = b.w;
        } else {
#pragma unroll
          for (int i = 0; i < 8; ++i) v[rf][i] = 0.f;
        }
      } else {
#pragma unroll
        for (int i = 0; i < 8; ++i) {
          int k = ks * 32 + khalf * 8 + i;
          v[rf][i] = (row < n && k < K) ? A[(size_t)row * K + k] : 0.f;
        }
      }
    }
  };

  loadA(0, vbuf[0]);

#pragma unroll
  for (int ks = 0; ks < KST; ++ks) {
    if (ks + 1 < KST) loadA(ks + 1, vbuf[(ks + 1) & 1]);
    bf16x8 ahi[4], alo[4];
#pragma unroll
    for (int rf = 0; rf < 4; ++rf)
#pragma unroll
      for (int i = 0; i < 8; ++i) {
        short hi, lo;
        split2(vbuf[ks & 1][rf][i], hi, lo);
        ahi[rf][i] = hi;
        alo[rf][i] = lo;
      }
#pragma unroll
    for (int cf = 0; cf < 8; ++cf) {
      int boff = ((ks * 8 + cf) * 64 + lane) * 8;
      bf16x8 bhi = *(bf16x8*)&Whi[boff];
      bf16x8 blo = *(bf16x8*)&Wlo[boff];
#pragma unroll
      for (int rf = 0; rf < 4; ++rf) {
        acc[rf][cf] = __builtin_amdgcn_mfma_f32_16x16x32_bf16(ahi[rf], bhi, acc[rf][cf], 0, 0, 0);
        acc[rf][cf] = __builtin_amdgcn_mfma_f32_16x16x32_bf16(ahi[rf], blo, acc[rf][cf], 0, 0, 0);
        acc[rf][cf] = __builtin_amdgcn_mfma_f32_16x16x32_bf16(alo[rf], bhi, acc[rf][cf], 0, 0, 0);
      }
    }
  }

#pragma unroll
  for (int rf = 0; rf < 4; ++rf)
#pragma unroll
    for (int cf = 0; cf < 8; ++cf) {
      int rowb = r0 + rf * 16 + khalf * 4;
      int col = cf * 16 + lrow;
#pragma unroll
      for (int j = 0; j < 4; ++j) {
        int row = rowb + j;
        if (row < n) out[(size_t)row * 128 + col] = acc[rf][cf][j];
      }
    }
}

// ---------------- degree count (int atomics) ----------------
__global__ void cnt_kernel(const int* __restrict__ ei, int* __restrict__ cnt, int e) {
  int i = blockIdx.x * blockDim.x + threadIdx.x;
  if (i < e) atomicAdd(&cnt[ei[(size_t)e + i]], 1);
}

__global__ void dinv_kernel(const int* __restrict__ cnt, float* __restrict__ dinv, int n) {
  int i = blockIdx.x * blockDim.x + threadIdx.x;
  if (i < n) dinv[i] = 1.0f / sqrtf((float)cnt[i] + 1.0f);
}

// ---------------- exclusive scan (3 kernels, 1024 elems/block) ----------------
__global__ __launch_bounds__(256) void scan1(const int* __restrict__ cnt, int* __restrict__ excl,
                                             int* __restrict__ partials, int n) {
  __shared__ int sd[256];
  int t = threadIdx.x;
  int base = blockIdx.x * 1024 + t * 4;
  int v[4]; int s = 0;
#pragma unroll
  for (int i = 0; i < 4; ++i) { int idx = base + i; v[i] = (idx < n) ? cnt[idx] : 0; s += v[i]; }
  sd[t] = s;
  __syncthreads();
  for (int off = 1; off < 256; off <<= 1) {
    int x = (t >= off) ? sd[t - off] : 0;
    __syncthreads();
    if (t >= off) sd[t] += x;
    __syncthreads();
  }
  if (t == 255) partials[blockIdx.x] = sd[255];
  int run = sd[t] - s;
#pragma unroll
  for (int i = 0; i < 4; ++i) { int idx = base + i; if (idx < n) excl[idx] = run; run += v[i]; }
}

__global__ __launch_bounds__(256) void scan2(int* __restrict__ partials, int np) {
  __shared__ int sd[256];
  int t = threadIdx.x;
  int v = (t < np) ? partials[t] : 0;
  sd[t] = v;
  __syncthreads();
  for (int off = 1; off < 256; off <<= 1) {
    int x = (t >= off) ? sd[t - off] : 0;
    __syncthreads();
    if (t >= off) sd[t] += x;
    __syncthreads();
  }
  if (t < np) partials[t] = sd[t] - v;
}

__global__ void scan3(int* __restrict__ rowptr, const int* __restrict__ partials, int n, int etot) {
  int i = blockIdx.x * blockDim.x + threadIdx.x;
  if (i < n) rowptr[i] += partials[i >> 10];
  if (i == 0) rowptr[n] = etot;
}

// ---------------- CSR fill: packed (src, coef) ----------------
__global__ void fill_kernel(const int* __restrict__ ei, const float* __restrict__ dinv,
                            const int* __restrict__ rowptr, int* __restrict__ cursor,
                            int2* __restrict__ epack, int e) {
  int i = blockIdx.x * blockDim.x + threadIdx.x;
  if (i >= e) return;
  int s = ei[i];
  int d = ei[(size_t)e + i];
  int p = atomicAdd(&cursor[d], 1);
  epack[rowptr[d] + p] = make_int2(s, __float_as_int(dinv[s] * dinv[d]));
}

// ---------------- aggregation: one wave per dst node, reg-cached edges ------
__global__ __launch_bounds__(256) void agg_kernel(
    const float* __restrict__ h, const float* __restrict__ dinv,
    const int* __restrict__ rowptr, const int2* __restrict__ epack,
    const float* __restrict__ bias, float* __restrict__ out, int n) {
  int wid = (int)((blockIdx.x * (size_t)blockDim.x + threadIdx.x) >> 6);
  int lane = threadIdx.x & 63;
  if (wid >= n) return;
  float di = dinv[wid];
  const float* hl = h + lane * 2;
  float2 hs = *(const float2*)(hl + (size_t)wid * HD);
  float2 a0, a1, a2, a3;
  a0.x = hs.x * di * di; a0.y = hs.y * di * di;
  a1.x = a1.y = a2.x = a2.y = a3.x = a3.y = 0.f;
  int beg = rowptr[wid], end = rowptr[wid + 1];
  while (beg < end) {
    int nj = end - beg;
    if (nj > 64) nj = 64;
    int2 ep = (lane < nj) ? epack[beg + lane] : make_int2(0, 0);
    int sreg = ep.x, creg = ep.y;
    int j = 0;
    for (; j + 4 <= nj; j += 4) {
      int s0 = __builtin_amdgcn_readlane(sreg, j + 0);
      int s1 = __builtin_amdgcn_readlane(sreg, j + 1);
      int s2 = __builtin_amdgcn_readlane(sreg, j + 2);
      int s3 = __builtin_amdgcn_readlane(sreg, j + 3);
      float c0 = __int_as_float(__builtin_amdgcn_readlane(creg, j + 0));
      float c1 = __int_as_float(__builtin_amdgcn_readlane(creg, j + 1));
      float c2 = __int_as_float(__builtin_amdgcn_readlane(creg, j + 2));
      float c3 = __int_as_float(__builtin_amdgcn_readlane(creg, j + 3));
      float2 v0 = *(const float2*)(hl + (size_t)s0 * HD);
      float2 v1 = *(const float2*)(hl + (size_t)s1 * HD);
      float2 v2 = *(const float2*)(hl + (size_t)s2 * HD);
      float2 v3 = *(const float2*)(hl + (size_t)s3 * HD);
      a0.x += v0.x * c0; a0.y += v0.y * c0;
      a1.x += v1.x * c1; a1.y += v1.y * c1;
      a2.x += v2.x * c2; a2.y += v2.y * c2;
      a3.x += v3.x * c3; a3.y += v3.y * c3;
    }
    for (; j < nj; ++j) {
      int s = __builtin_amdgcn_readlane(sreg, j);
      float c = __int_as_float(__builtin_amdgcn_readlane(creg, j));
      float2 v = *(const float2*)(hl + (size_t)s * HD);
      a0.x += v.x * c; a0.y += v.y * c;
    }
    beg += nj;
  }
  float2 b = *(const float2*)(bias + lane * 2);
  float2 o;
  o.x = tanhf((a0.x + a1.x) + (a2.x + a3.x) + b.x);
  o.y = tanhf((a0.y + a1.y) + (a2.y + a3.y) + b.y);
  *(float2*)(out + (size_t)wid * HD + lane * 2) = o;
}

extern "C" void kernel_launch(void* const* d_in, const int* in_sizes, int n_in,
                              void* d_out, int out_size, void* d_ws, size_t ws_size,
                              hipStream_t stream) {
  const float* x = (const float*)d_in[0];
  const int* ei = (const int*)d_in[1];   // integer inputs arrive as int32
  const float* W0 = (const float*)d_in[2];
  const float* b0 = (const float*)d_in[3];
  const float* W1 = (const float*)d_in[4];
  const float* b1 = (const float*)d_in[5];
  const float* W2 = (const float*)d_in[6];
  const float* b2 = (const float*)d_in[7];
  const float* W3 = (const float*)d_in[8];
  const float* b3 = (const float*)d_in[9];
  float* out = (float*)d_out;

  char* ws = (char*)d_ws;
  size_t off = 0;
  auto alloc = [&](size_t bytes) -> void* {
    void* p = ws + off;
    off += (bytes + 255) & ~(size_t)255;
    return p;
  };
  int*   cnt      = (int*)alloc((size_t)NN * 4);
  int*   cursor   = (int*)alloc((size_t)NN * 4);
  int*   rowptr   = (int*)alloc((size_t)(NN + 1) * 4);
  int*   partials = (int*)alloc(256 * 4);
  float* dinv     = (float*)alloc((size_t)NN * 4);
  int2*  epack    = (int2*)alloc((size_t)NE * 8);
  float* hbuf     = (float*)alloc((size_t)NN * HD * 4);
  // ~66 MB ws. d_out doubles as the activation ping-pong buffer.

  hipMemsetAsync(cnt, 0, (size_t)NN * 4, stream);
  hipMemsetAsync(cursor, 0, (size_t)NN * 4, stream);

  int eb = (NE + 255) / 256;
  cnt_kernel<<<eb, 256, 0, stream>>>(ei, cnt, NE);
  int nb1 = (NN + 1023) / 1024;
  scan1<<<nb1, 256, 0, stream>>>(cnt, rowptr, partials, NN);
  scan2<<<1, 256, 0, stream>>>(partials, nb1);
  scan3<<<(NN + 255) / 256, 256, 0, stream>>>(rowptr, partials, NN, NE);
  dinv_kernel<<<(NN + 255) / 256, 256, 0, stream>>>(cnt, dinv, NN);
  fill_kernel<<<eb, 256, 0, stream>>>(ei, dinv, rowptr, cursor, epack, NE);

  int gb = (NN + 255) / 256;   // 256 rows per block
  int ab = (NN + 3) / 4;       // 1 wave per node

  // layer 0: x -> hbuf -> d_out   (K=133, unaligned rows -> scalar A loads)
  mfma_gemm<5, false><<<gb, 256, 0, stream>>>(x, W0, hbuf, NN, 133);
  agg_kernel<<<ab, 256, 0, stream>>>(hbuf, dinv, rowptr, epack, b0, out, NN);
  // layers 1-3: K=128, vectorized A loads
  mfma_gemm<4, true><<<gb, 256, 0, stream>>>(out, W1, hbuf, NN, HD);
  agg_kernel<<<ab, 256, 0, stream>>>(hbuf, dinv, rowptr, epack, b1, out, NN);
  mfma_gemm<4, true><<<gb, 256, 0, stream>>>(out, W2, hbuf, NN, HD);
  agg_kernel<<<ab, 256, 0, stream>>>(hbuf, dinv, rowptr, epack, b2, out, NN);
  mfma_gemm<4, true><<<gb, 256, 0, stream>>>(out, W3, hbuf, NN, HD);
  agg_kernel<<<ab, 256, 0, stream>>>(hbuf, dinv, rowptr, epack, b3, out, NN);
}